// Round 6
// baseline (336.819 us; speedup 1.0000x reference)
//
#include <hip/hip_runtime.h>

// GatedAttentionUnit: B=4, S=2048, D=768, I=1536, H=128. All-bf16 MFMA pipeline
// (fp8 fails the absmax-over-6M-elements threshold: 3.6% RMS/tensor vs 2% budget).
// All GEMM K-loops use explicit LDS double-buffering: stage(t+1) issued BEFORE
// compute(t), one barrier per iter -> load latency overlapped by compute phase.
//  G123 : x @ [vW gW inW] (M=8192,N=3200,K=768) -> vt (transposed), gateT, q, k
//  SC   : k@q^T (K=128, single-stage LDS, 1 barrier); P = relu(./sqrt(I)+bias)^2, triangular grid
//  OG   : og = (P@v)*gate, XCD-aware LPT flat grid, causal K-clamp
//  GOUT : out = og@outW + ob (fp32), 64x128 tiles, n-sliced XCD swizzle

typedef short short8 __attribute__((ext_vector_type(8)));
typedef float f32x4 __attribute__((ext_vector_type(4)));
typedef unsigned short us4 __attribute__((ext_vector_type(4)));
typedef float fl4 __attribute__((ext_vector_type(4)));

__device__ __forceinline__ unsigned short f2bf(float f) {
  unsigned u = __builtin_bit_cast(unsigned, f);
  u += 0x7FFFu + ((u >> 16) & 1u);
  return (unsigned short)(u >> 16);
}
__device__ __forceinline__ float bf2f(unsigned short b) {
  return __builtin_bit_cast(float, ((unsigned)b) << 16);
}
__device__ __forceinline__ float silu_f(float x) { return x / (1.0f + __expf(-x)); }

__device__ __forceinline__ void gl_lds16(const void* gp, void* lp) {
  __builtin_amdgcn_global_load_lds((const __attribute__((address_space(1))) void*)gp,
                                   (__attribute__((address_space(3))) void*)lp, 16, 0, 0);
}

// 128 rows x 64 cols bf16 tile (16 KB): 4 calls/wave x 16B/lane
__device__ __forceinline__ void stage_bf(const unsigned short* __restrict__ g,
                                         int row_stride, int r0, int ko,
                                         unsigned short* lds, int w, int l) {
#pragma unroll
  for (int c = 0; c < 4; ++c) {
    int e = ((w * 4 + c) << 9) + l * 8;
    gl_lds16(g + (size_t)(r0 + (e >> 6)) * row_stride + (ko + (e & 63)), lds + e);
  }
}
// 64 rows x 64 cols bf16 tile (8 KB): 2 calls/wave
__device__ __forceinline__ void stage_bf64(const unsigned short* __restrict__ g,
                                           int row_stride, int r0, int ko,
                                           unsigned short* lds, int w, int l) {
#pragma unroll
  for (int c = 0; c < 2; ++c) {
    int e = ((w * 2 + c) << 9) + l * 8;
    gl_lds16(g + (size_t)(r0 + (e >> 6)) * row_stride + (ko + (e & 63)), lds + e);
  }
}

// 128x128 tile K-step over BK=64 (stride 64): 32 MFMA
__device__ __forceinline__ void mfma_bf(const unsigned short* As, const unsigned short* Bs,
                                        f32x4 acc[4][4], int wm, int wn, int quad, int lc) {
#pragma unroll
  for (int kk = 0; kk < 2; ++kk) {
    short8 af[4], bfr[4];
#pragma unroll
    for (int i = 0; i < 4; ++i)
      af[i] = *(const short8*)&As[(wm + i * 16 + lc) * 64 + kk * 32 + quad * 8];
#pragma unroll
    for (int j = 0; j < 4; ++j)
      bfr[j] = *(const short8*)&Bs[(wn + j * 16 + lc) * 64 + kk * 32 + quad * 8];
#pragma unroll
    for (int i = 0; i < 4; ++i)
#pragma unroll
      for (int j = 0; j < 4; ++j)
        acc[i][j] = __builtin_amdgcn_mfma_f32_16x16x32_bf16(af[i], bfr[j], acc[i][j], 0, 0, 0);
  }
}

// ---------------- G123: x @ [vW gW inW], dbuf ----------------
__global__ __launch_bounds__(256) void g123_k(
    const unsigned short* __restrict__ X,    // 8192x768
    const unsigned short* __restrict__ Wst,  // 3200x768 (stacked W^T)
    unsigned short* __restrict__ vt,         // [4][1536][2048]
    unsigned short* __restrict__ gateT,      // [1536][8192]
    unsigned short* __restrict__ wq,         // [8192][128]
    unsigned short* __restrict__ wk,
    const float* __restrict__ v_b, const float* __restrict__ g_b,
    const float* __restrict__ in_b, const float* __restrict__ q_g,
    const float* __restrict__ q_be, const float* __restrict__ k_g,
    const float* __restrict__ k_be) {
  __shared__ unsigned short As[2][128 * 64];
  __shared__ unsigned short Bs[2][128 * 64];
  const int t = threadIdx.x, l = t & 63, w = t >> 6;
  const int id = blockIdx.x;
  const int xcd = id & 7, rest = id >> 3;
  const int n = rest % 25, m = (rest / 25) * 8 + xcd;
  const int m0 = m * 128, n0 = n * 128;
  const int wm = (w >> 1) * 64, wn = (w & 1) * 64;
  const int quad = l >> 4, lr = quad * 4, lc = l & 15;

  f32x4 acc[4][4] = {};
  stage_bf(X, 768, m0, 0, As[0], w, l);
  stage_bf(Wst, 768, n0, 0, Bs[0], w, l);
  __syncthreads();
  int cur = 0;
  for (int tt = 1; tt < 12; ++tt) {  // K=768 -> 12 tiles
    stage_bf(X, 768, m0, tt * 64, As[cur ^ 1], w, l);
    stage_bf(Wst, 768, n0, tt * 64, Bs[cur ^ 1], w, l);
    mfma_bf(As[cur], Bs[cur], acc, wm, wn, quad, lc);
    __syncthreads();
    cur ^= 1;
  }
  mfma_bf(As[cur], Bs[cur], acc, wm, wn, quad, lc);

#pragma unroll
  for (int i = 0; i < 4; ++i) {
    const int gm = m0 + wm + i * 16 + lr;  // bs row
#pragma unroll
    for (int j = 0; j < 4; ++j) {
      const int gn = n0 + wn + j * 16 + lc;  // stacked col
      f32x4 a = acc[i][j];
      if (n0 < 1536) {  // v -> vt[b][i][s], 4 consecutive s
        float bv = v_b[gn];
        us4 pk;
#pragma unroll
        for (int r = 0; r < 4; ++r) pk[r] = f2bf(silu_f(a[r] + bv));
        size_t off = (size_t)(gm >> 11) * (1536 * 2048) + (size_t)gn * 2048 + (gm & 2047);
        *(us4*)&vt[off] = pk;
      } else if (n0 < 3072) {  // gateT[i][bs]
        float bv = g_b[gn - 1536];
        us4 pk;
#pragma unroll
        for (int r = 0; r < 4; ++r) pk[r] = f2bf(silu_f(a[r] + bv));
        *(us4*)&gateT[(size_t)(gn - 1536) * 8192 + gm] = pk;
      } else {  // qk: scalar bf16 stores (lanes span h -> coalesced)
        int h = gn - 3072;
        float bb = in_b[h], qg = q_g[h], qb = q_be[h], kg = k_g[h], kb = k_be[h];
#pragma unroll
        for (int r = 0; r < 4; ++r) {
          float s = silu_f(a[r] + bb);
          wq[(size_t)(gm + r) * 128 + h] = f2bf(s * qg + qb);
          wk[(size_t)(gm + r) * 128 + h] = f2bf(s * kg + kb);
        }
      }
    }
  }
}

// ---------------- SC: k@q^T, K=128 fully staged, 1 barrier ----------------
__global__ __launch_bounds__(256) void scores_k(
    const unsigned short* __restrict__ wk, const unsigned short* __restrict__ wq,
    unsigned short* __restrict__ P, const float* __restrict__ btab) {
  __shared__ unsigned short As[128 * 128];  // 32 KB
  __shared__ unsigned short Bs[128 * 128];
  const int t = threadIdx.x, l = t & 63, w = t >> 6;
  const int z = blockIdx.z;
  int ti = blockIdx.x;  // triangular decode: c <= r
  int r = (int)((sqrtf((float)(8 * ti + 1)) - 1.0f) * 0.5f);
  if ((r + 1) * (r + 2) / 2 <= ti) ++r;
  int c = ti - r * (r + 1) / 2;
  const int m0 = c * 128, n0 = r * 128;
  const unsigned short* A = wk + (size_t)z * 2048 * 128;
  const unsigned short* Bt = wq + (size_t)z * 2048 * 128;
  unsigned short* Pz = P + (size_t)z * 2048 * 2048;
  const int wm = (w >> 1) * 64, wn = (w & 1) * 64;
  const int quad = l >> 4, lr = quad * 4, lc = l & 15;

  // stage full 128x128 tiles: 8 calls each
#pragma unroll
  for (int cc = 0; cc < 8; ++cc) {
    int e = ((w * 8 + cc) << 9) + l * 8;
    gl_lds16(A + (size_t)(m0 + (e >> 7)) * 128 + (e & 127), As + e);
  }
#pragma unroll
  for (int cc = 0; cc < 8; ++cc) {
    int e = ((w * 8 + cc) << 9) + l * 8;
    gl_lds16(Bt + (size_t)(n0 + (e >> 7)) * 128 + (e & 127), Bs + e);
  }
  __syncthreads();

  f32x4 acc[4][4] = {};
#pragma unroll
  for (int kk = 0; kk < 4; ++kk) {
    short8 af[4], bfr[4];
#pragma unroll
    for (int i = 0; i < 4; ++i)
      af[i] = *(const short8*)&As[(wm + i * 16 + lc) * 128 + kk * 32 + quad * 8];
#pragma unroll
    for (int j = 0; j < 4; ++j)
      bfr[j] = *(const short8*)&Bs[(wn + j * 16 + lc) * 128 + kk * 32 + quad * 8];
#pragma unroll
    for (int i = 0; i < 4; ++i)
#pragma unroll
      for (int j = 0; j < 4; ++j)
        acc[i][j] = __builtin_amdgcn_mfma_f32_16x16x32_bf16(af[i], bfr[j], acc[i][j], 0, 0, 0);
  }

  const float SCALE = 0.025515518153991442f;  // 1/sqrt(1536)
#pragma unroll
  for (int i = 0; i < 4; ++i) {
    const int gm = m0 + wm + i * 16 + lr;  // s'
#pragma unroll
    for (int j = 0; j < 4; ++j) {
      const int gn = n0 + wn + j * 16 + lc;  // s
      us4 pk;
#pragma unroll
      for (int r2 = 0; r2 < 4; ++r2) {
        int mm = gm + r2;
        float v = 0.0f;
        if (mm <= gn) {
          float tt = fmaf(acc[i][j][r2], SCALE, btab[gn - mm]);
          tt = fmaxf(tt, 0.0f);
          v = tt * tt;
        }
        pk[r2] = f2bf(v);
      }
      *(us4*)&Pz[(size_t)gn * 2048 + gm] = pk;
    }
  }
}

// ---------------- OG: (P@v)*gate, XCD-aware LPT, dbuf ----------------
__global__ __launch_bounds__(256) void og_k(
    const unsigned short* __restrict__ Vt,     // [4][1536][2048]
    const unsigned short* __restrict__ P,      // [4][2048][2048]
    const unsigned short* __restrict__ gateT,  // [1536][8192]
    unsigned short* __restrict__ og) {         // [8192][1536]
  __shared__ unsigned short As[2][128 * 64];
  __shared__ unsigned short Bs[2][128 * 64];
  const int t = threadIdx.x, l = t & 63, w = t >> 6;
  const int id = blockIdx.x;
  const int bblk = id / 96, rr = id % 96;
  const int xcd = rr & 7, mi = rr >> 3;
  const int half = xcd >> 2, z = xcd & 3;
  const int nt = 15 - 2 * bblk - (half ^ (bblk & 1));
  const int m0 = mi * 128;    // I tile
  const int n0 = nt * 128;    // S tile
  const int T = (n0 + 128) >> 6;  // causal extent in BK=64 tiles (>=2)
  const unsigned short* A = Vt + (size_t)z * 1536 * 2048;
  const unsigned short* B = P + (size_t)z * 2048 * 2048;
  const int wm = (w >> 1) * 64, wn = (w & 1) * 64;
  const int quad = l >> 4, lr = quad * 4, lc = l & 15;

  f32x4 acc[4][4] = {};
  stage_bf(A, 2048, m0, 0, As[0], w, l);
  stage_bf(B, 2048, n0, 0, Bs[0], w, l);
  __syncthreads();
  int cur = 0;
  for (int tt = 1; tt < T; ++tt) {
    stage_bf(A, 2048, m0, tt * 64, As[cur ^ 1], w, l);
    stage_bf(B, 2048, n0, tt * 64, Bs[cur ^ 1], w, l);
    mfma_bf(As[cur], Bs[cur], acc, wm, wn, quad, lc);
    __syncthreads();
    cur ^= 1;
  }
  mfma_bf(As[cur], Bs[cur], acc, wm, wn, quad, lc);

#pragma unroll
  for (int i = 0; i < 4; ++i) {
    const int gm = m0 + wm + i * 16 + lr;  // i
#pragma unroll
    for (int j = 0; j < 4; ++j) {
      const int gn = n0 + wn + j * 16 + lc;  // s
      us4 pk;
#pragma unroll
      for (int r2 = 0; r2 < 4; ++r2) {
        float g = bf2f(gateT[(size_t)(gm + r2) * 8192 + z * 2048 + gn]);
        pk[r2] = f2bf(acc[i][j][r2] * g);
      }
      *(us4*)&og[((size_t)z * 2048 + gn) * 1536 + gm] = pk;
    }
  }
}

// ---------------- GOUT: og @ outW + ob, 64x128 tiles, dbuf ----------------
__global__ __launch_bounds__(256) void gout_k(
    const unsigned short* __restrict__ A,   // oWt 768x1536
    const unsigned short* __restrict__ Bt,  // og 8192x1536
    float* __restrict__ out, const float* __restrict__ o_b) {
  __shared__ unsigned short As[2][64 * 64];   // 8 KB each
  __shared__ unsigned short Bs[2][128 * 64];  // 16 KB each
  const int t = threadIdx.x, l = t & 63, w = t >> 6;
  // 768 blocks: xcd = id&7; each XCD: n in {ng*8+xcd} x all 12 m -> B-slab 3.1 MB in L2
  const int id = blockIdx.x;
  const int xcd = id & 7, rest = id >> 3;
  const int m = rest % 12, ng = rest / 12;
  const int m0 = m * 64, n0 = (ng * 8 + xcd) * 128;
  const int wm = (w >> 1) * 32, wn = (w & 1) * 64;
  const int quad = l >> 4, lr = quad * 4, lc = l & 15;

  f32x4 acc[2][4] = {};
  stage_bf64(A, 1536, m0, 0, As[0], w, l);
  stage_bf(Bt, 1536, n0, 0, Bs[0], w, l);
  __syncthreads();
  int cur = 0;
  for (int tt = 1; tt < 24; ++tt) {  // K=1536 -> 24 tiles
    stage_bf64(A, 1536, m0, tt * 64, As[cur ^ 1], w, l);
    stage_bf(Bt, 1536, n0, tt * 64, Bs[cur ^ 1], w, l);
#pragma unroll
    for (int kk = 0; kk < 2; ++kk) {
      short8 af[2], bfr[4];
#pragma unroll
      for (int i = 0; i < 2; ++i)
        af[i] = *(const short8*)&As[cur][(wm + i * 16 + lc) * 64 + kk * 32 + quad * 8];
#pragma unroll
      for (int j = 0; j < 4; ++j)
        bfr[j] = *(const short8*)&Bs[cur][(wn + j * 16 + lc) * 64 + kk * 32 + quad * 8];
#pragma unroll
      for (int i = 0; i < 2; ++i)
#pragma unroll
        for (int j = 0; j < 4; ++j)
          acc[i][j] = __builtin_amdgcn_mfma_f32_16x16x32_bf16(af[i], bfr[j], acc[i][j], 0, 0, 0);
    }
    __syncthreads();
    cur ^= 1;
  }
#pragma unroll
  for (int kk = 0; kk < 2; ++kk) {
    short8 af[2], bfr[4];
#pragma unroll
    for (int i = 0; i < 2; ++i)
      af[i] = *(const short8*)&As[cur][(wm + i * 16 + lc) * 64 + kk * 32 + quad * 8];
#pragma unroll
    for (int j = 0; j < 4; ++j)
      bfr[j] = *(const short8*)&Bs[cur][(wn + j * 16 + lc) * 64 + kk * 32 + quad * 8];
#pragma unroll
    for (int i = 0; i < 2; ++i)
#pragma unroll
      for (int j = 0; j < 4; ++j)
        acc[i][j] = __builtin_amdgcn_mfma_f32_16x16x32_bf16(af[i], bfr[j], acc[i][j], 0, 0, 0);
  }

#pragma unroll
  for (int i = 0; i < 2; ++i) {
    const int gm = m0 + wm + i * 16 + lr;  // d
#pragma unroll
    for (int j = 0; j < 4; ++j) {
      const int gn = n0 + wn + j * 16 + lc;  // bs
      fl4 ob = *(const fl4*)&o_b[gm];
      fl4 res;
#pragma unroll
      for (int r2 = 0; r2 < 4; ++r2) res[r2] = acc[i][j][r2] + ob[r2];
      *(fl4*)&out[(size_t)gn * 768 + gm] = res;
    }
  }
}

// ---------------- prep ----------------
__global__ void cvt_bf16(const float* __restrict__ in, unsigned short* __restrict__ out, int n) {
  int i = (blockIdx.x * blockDim.x + threadIdx.x) * 4;
  if (i < n) {
    fl4 v = *(const fl4*)&in[i];
    us4 o;
#pragma unroll
    for (int r = 0; r < 4; ++r) o[r] = f2bf(v[r]);
    *(us4*)&out[i] = o;
  }
}

__global__ void transpose_cvt4(const float* __restrict__ s0, unsigned short* __restrict__ d0,
                               const float* __restrict__ s1, unsigned short* __restrict__ d1,
                               const float* __restrict__ s2, unsigned short* __restrict__ d2,
                               const float* __restrict__ s3, unsigned short* __restrict__ d3) {
  __shared__ float tile[32][33];
  const float* in;
  unsigned short* out;
  int K_, N_, bxm, bym;
  switch (blockIdx.z) {
    case 0: in = s0; out = d0; K_ = 768; N_ = 1536; bxm = 48; bym = 24; break;
    case 1: in = s1; out = d1; K_ = 768; N_ = 1536; bxm = 48; bym = 24; break;
    case 2: in = s2; out = d2; K_ = 768; N_ = 128;  bxm = 4;  bym = 24; break;
    default: in = s3; out = d3; K_ = 1536; N_ = 768; bxm = 24; bym = 48; break;
  }
  if ((int)blockIdx.x >= bxm || (int)blockIdx.y >= bym) return;
  int bn = blockIdx.x * 32, bk = blockIdx.y * 32;
  int tx = threadIdx.x, ty = threadIdx.y;
#pragma unroll
  for (int i2 = 0; i2 < 32; i2 += 8)
    tile[ty + i2][tx] = in[(size_t)(bk + ty + i2) * N_ + (bn + tx)];
  __syncthreads();
#pragma unroll
  for (int i2 = 0; i2 < 32; i2 += 8)
    out[(size_t)(bn + ty + i2) * K_ + (bk + tx)] = f2bf(tile[tx][ty + i2]);
}

__global__ void build_bias(const float* __restrict__ rel_emb, float* __restrict__ tab) {
  int d = blockIdx.x * blockDim.x + threadIdx.x;
  if (d < 2048) {
    int bucket;
    if (d < 16) {
      bucket = d;
    } else {
      float n = (float)d;
      int vl = 16 + (int)((logf(n * 0.0625f) / logf(8.0f)) * 16.0f);
      bucket = vl < 31 ? vl : 31;
    }
    tab[d] = rel_emb[bucket] * 11.3137085f;
  }
}

extern "C" void kernel_launch(void* const* d_in, const int* in_sizes, int n_in,
                              void* d_out, int out_size, void* d_ws, size_t ws_size,
                              hipStream_t stream) {
  const float* x    = (const float*)d_in[0];
  const float* vW   = (const float*)d_in[1];
  const float* v_b  = (const float*)d_in[2];
  const float* gW   = (const float*)d_in[3];
  const float* g_b  = (const float*)d_in[4];
  const float* inW  = (const float*)d_in[5];
  const float* in_b = (const float*)d_in[6];
  const float* q_g  = (const float*)d_in[7];
  const float* q_be = (const float*)d_in[8];
  const float* k_g  = (const float*)d_in[9];
  const float* k_be = (const float*)d_in[10];
  const float* oW   = (const float*)d_in[11];
  const float* o_b  = (const float*)d_in[12];
  const float* rel  = (const float*)d_in[13];

  char* p = (char*)d_ws;
  auto alloc = [&](size_t bytes) -> char* {
    char* r = p;
    p += (bytes + 255) & ~(size_t)255;
    return r;
  };
  unsigned short* x_bf   = (unsigned short*)alloc(8192ull * 768 * 2);
  unsigned short* wstack = (unsigned short*)alloc(3200ull * 768 * 2);  // [vWt;gWt;inWt]
  unsigned short* vWt  = wstack;
  unsigned short* gWt  = wstack + 1536ull * 768;
  unsigned short* inWt = wstack + 3072ull * 768;
  unsigned short* oWt  = (unsigned short*)alloc(768ull * 1536 * 2);
  unsigned short* wq   = (unsigned short*)alloc(8192ull * 128 * 2);
  unsigned short* wk   = (unsigned short*)alloc(8192ull * 128 * 2);
  unsigned short* vt   = (unsigned short*)alloc(4ull * 1536 * 2048 * 2);
  unsigned short* gateT= (unsigned short*)alloc(1536ull * 8192 * 2);
  unsigned short* P    = (unsigned short*)alloc(4ull * 2048 * 2048 * 2);
  unsigned short* og   = (unsigned short*)alloc(8192ull * 1536 * 2);
  float* btab          = (float*)alloc(2048 * 4);

  cvt_bf16<<<dim3(6144), dim3(256), 0, stream>>>(x, x_bf, 8192 * 768);
  transpose_cvt4<<<dim3(48, 48, 4), dim3(32, 8), 0, stream>>>(vW, vWt, gW, gWt, inW, inWt, oW, oWt);
  build_bias<<<dim3(8), dim3(256), 0, stream>>>(rel, btab);

  g123_k<<<dim3(1600), 256, 0, stream>>>(x_bf, wstack, vt, gateT, wq, wk,
                                         v_b, g_b, in_b, q_g, q_be, k_g, k_be);
  scores_k<<<dim3(136, 1, 4), 256, 0, stream>>>(wk, wq, P, btab);
  og_k<<<dim3(768), 256, 0, stream>>>(vt, P, gateT, og);
  gout_k<<<dim3(768), 256, 0, stream>>>(oWt, og, (float*)d_out, o_b);
}

// Round 7
// 320.272 us; speedup vs baseline: 1.0517x; 1.0517x over previous
//
#include <hip/hip_runtime.h>

// GatedAttentionUnit: B=4, S=2048, D=768, I=1536, H=128. All-bf16 MFMA pipeline.
// Single-buffered 2-barrier K-loops (explicit dbuf regressed: __syncthreads drains
// the prefetch vmcnt too — R6). g123 uses 256x128 tiles: 64 MFMA/wave per barrier.
//  G123 : x @ [vW gW inW] (M=8192,N=3200,K=768) -> vt (transposed), gateT, q, k
//  SC   : k@q^T (K=128 single-stage LDS, 1 barrier); P = relu(./sqrt(I)+bias)^2, triangular
//  OG   : og = (P@v)*gate, 128x128, XCD-aware LPT flat grid, causal K-clamp
//  GOUT : out = og@outW + ob (fp32), 64x128 tiles, 768 blocks (3/CU exact)

typedef short short8 __attribute__((ext_vector_type(8)));
typedef float f32x4 __attribute__((ext_vector_type(4)));
typedef unsigned short us4 __attribute__((ext_vector_type(4)));
typedef float fl4 __attribute__((ext_vector_type(4)));

__device__ __forceinline__ unsigned short f2bf(float f) {
  unsigned u = __builtin_bit_cast(unsigned, f);
  u += 0x7FFFu + ((u >> 16) & 1u);
  return (unsigned short)(u >> 16);
}
__device__ __forceinline__ float bf2f(unsigned short b) {
  return __builtin_bit_cast(float, ((unsigned)b) << 16);
}
__device__ __forceinline__ float silu_f(float x) { return x / (1.0f + __expf(-x)); }

__device__ __forceinline__ void gl_lds16(const void* gp, void* lp) {
  __builtin_amdgcn_global_load_lds((const __attribute__((address_space(1))) void*)gp,
                                   (__attribute__((address_space(3))) void*)lp, 16, 0, 0);
}

// 128x64 bf16 tile (16 KB): 4 calls/wave
__device__ __forceinline__ void stage_bf(const unsigned short* __restrict__ g,
                                         int row_stride, int r0, int ko,
                                         unsigned short* lds, int w, int l) {
#pragma unroll
  for (int c = 0; c < 4; ++c) {
    int e = ((w * 4 + c) << 9) + l * 8;
    gl_lds16(g + (size_t)(r0 + (e >> 6)) * row_stride + (ko + (e & 63)), lds + e);
  }
}
// 256x64 bf16 tile (32 KB): 8 calls/wave
__device__ __forceinline__ void stage_bf256(const unsigned short* __restrict__ g,
                                            int row_stride, int r0, int ko,
                                            unsigned short* lds, int w, int l) {
#pragma unroll
  for (int c = 0; c < 8; ++c) {
    int e = ((w * 8 + c) << 9) + l * 8;
    gl_lds16(g + (size_t)(r0 + (e >> 6)) * row_stride + (ko + (e & 63)), lds + e);
  }
}
// 64x64 bf16 tile (8 KB): 2 calls/wave
__device__ __forceinline__ void stage_bf64(const unsigned short* __restrict__ g,
                                           int row_stride, int r0, int ko,
                                           unsigned short* lds, int w, int l) {
#pragma unroll
  for (int c = 0; c < 2; ++c) {
    int e = ((w * 2 + c) << 9) + l * 8;
    gl_lds16(g + (size_t)(r0 + (e >> 6)) * row_stride + (ko + (e & 63)), lds + e);
  }
}

// 128x128 K-step over BK=64: 32 MFMA/wave
__device__ __forceinline__ void mfma_bf(const unsigned short* As, const unsigned short* Bs,
                                        f32x4 acc[4][4], int wm, int wn, int quad, int lc) {
#pragma unroll
  for (int kk = 0; kk < 2; ++kk) {
    short8 af[4], bfr[4];
#pragma unroll
    for (int i = 0; i < 4; ++i)
      af[i] = *(const short8*)&As[(wm + i * 16 + lc) * 64 + kk * 32 + quad * 8];
#pragma unroll
    for (int j = 0; j < 4; ++j)
      bfr[j] = *(const short8*)&Bs[(wn + j * 16 + lc) * 64 + kk * 32 + quad * 8];
#pragma unroll
    for (int i = 0; i < 4; ++i)
#pragma unroll
      for (int j = 0; j < 4; ++j)
        acc[i][j] = __builtin_amdgcn_mfma_f32_16x16x32_bf16(af[i], bfr[j], acc[i][j], 0, 0, 0);
  }
}

// ---------------- G123: x @ [vW gW inW], 256x128 tiles ----------------
__global__ __launch_bounds__(256, 2) void g123_k(
    const unsigned short* __restrict__ X,    // 8192x768
    const unsigned short* __restrict__ Wst,  // 3200x768 (stacked W^T)
    unsigned short* __restrict__ vt,         // [4][1536][2048]
    unsigned short* __restrict__ gateT,      // [1536][8192]
    unsigned short* __restrict__ wq,         // [8192][128]
    unsigned short* __restrict__ wk,
    const float* __restrict__ v_b, const float* __restrict__ g_b,
    const float* __restrict__ in_b, const float* __restrict__ q_g,
    const float* __restrict__ q_be, const float* __restrict__ k_g,
    const float* __restrict__ k_be) {
  __shared__ unsigned short As[256 * 64];  // 32 KB
  __shared__ unsigned short Bs[128 * 64];  // 16 KB
  const int t = threadIdx.x, l = t & 63, w = t >> 6;
  // 800 blocks: id&7 -> XCD; each XCD: 4 m-tiles (x-slab 1.6MB L2-resident) x 25 n.
  const int id = blockIdx.x;
  const int xcd = id & 7, rest = id >> 3;
  const int n = rest % 25, m = (rest / 25) * 8 + xcd;  // m in 0..31
  const int m0 = m * 256, n0 = n * 128;
  const int wm = (w >> 1) * 128, wn = (w & 1) * 64;  // wave sub-tile 128m x 64n
  const int quad = l >> 4, lr = quad * 4, lc = l & 15;

  f32x4 acc[8][4] = {};
  for (int ko = 0; ko < 768; ko += 64) {
    stage_bf256(X, 768, m0, ko, As, w, l);
    stage_bf(Wst, 768, n0, ko, Bs, w, l);
    __syncthreads();
#pragma unroll
    for (int kk = 0; kk < 2; ++kk) {
      short8 af[8], bfr[4];
#pragma unroll
      for (int i = 0; i < 8; ++i)
        af[i] = *(const short8*)&As[(wm + i * 16 + lc) * 64 + kk * 32 + quad * 8];
#pragma unroll
      for (int j = 0; j < 4; ++j)
        bfr[j] = *(const short8*)&Bs[(wn + j * 16 + lc) * 64 + kk * 32 + quad * 8];
#pragma unroll
      for (int i = 0; i < 8; ++i)
#pragma unroll
        for (int j = 0; j < 4; ++j)
          acc[i][j] = __builtin_amdgcn_mfma_f32_16x16x32_bf16(af[i], bfr[j], acc[i][j], 0, 0, 0);
    }
    __syncthreads();
  }

#pragma unroll
  for (int i = 0; i < 8; ++i) {
    const int gm = m0 + wm + i * 16 + lr;  // bs row
#pragma unroll
    for (int j = 0; j < 4; ++j) {
      const int gn = n0 + wn + j * 16 + lc;  // stacked col
      f32x4 a = acc[i][j];
      if (n0 < 1536) {  // v -> vt[b][i][s], 4 consecutive s
        float bv = v_b[gn];
        us4 pk;
#pragma unroll
        for (int r = 0; r < 4; ++r) pk[r] = f2bf(silu_f(a[r] + bv));
        size_t off = (size_t)(gm >> 11) * (1536 * 2048) + (size_t)gn * 2048 + (gm & 2047);
        *(us4*)&vt[off] = pk;
      } else if (n0 < 3072) {  // gateT[i][bs]
        float bv = g_b[gn - 1536];
        us4 pk;
#pragma unroll
        for (int r = 0; r < 4; ++r) pk[r] = f2bf(silu_f(a[r] + bv));
        *(us4*)&gateT[(size_t)(gn - 1536) * 8192 + gm] = pk;
      } else {  // qk: scalar bf16 stores (lanes span h -> coalesced)
        int h = gn - 3072;
        float bb = in_b[h], qg = q_g[h], qb = q_be[h], kg = k_g[h], kb = k_be[h];
#pragma unroll
        for (int r = 0; r < 4; ++r) {
          float s = silu_f(a[r] + bb);
          wq[(size_t)(gm + r) * 128 + h] = f2bf(s * qg + qb);
          wk[(size_t)(gm + r) * 128 + h] = f2bf(s * kg + kb);
        }
      }
    }
  }
}

// ---------------- SC: k@q^T, K=128 fully staged, 1 barrier ----------------
__global__ __launch_bounds__(256) void scores_k(
    const unsigned short* __restrict__ wk, const unsigned short* __restrict__ wq,
    unsigned short* __restrict__ P, const float* __restrict__ btab) {
  __shared__ unsigned short As[128 * 128];  // 32 KB
  __shared__ unsigned short Bs[128 * 128];
  const int t = threadIdx.x, l = t & 63, w = t >> 6;
  const int z = blockIdx.z;
  int ti = blockIdx.x;  // triangular decode: c <= r
  int r = (int)((sqrtf((float)(8 * ti + 1)) - 1.0f) * 0.5f);
  if ((r + 1) * (r + 2) / 2 <= ti) ++r;
  int c = ti - r * (r + 1) / 2;
  const int m0 = c * 128, n0 = r * 128;
  const unsigned short* A = wk + (size_t)z * 2048 * 128;
  const unsigned short* Bt = wq + (size_t)z * 2048 * 128;
  unsigned short* Pz = P + (size_t)z * 2048 * 2048;
  const int wm = (w >> 1) * 64, wn = (w & 1) * 64;
  const int quad = l >> 4, lr = quad * 4, lc = l & 15;

#pragma unroll
  for (int cc = 0; cc < 8; ++cc) {
    int e = ((w * 8 + cc) << 9) + l * 8;
    gl_lds16(A + (size_t)(m0 + (e >> 7)) * 128 + (e & 127), As + e);
  }
#pragma unroll
  for (int cc = 0; cc < 8; ++cc) {
    int e = ((w * 8 + cc) << 9) + l * 8;
    gl_lds16(Bt + (size_t)(n0 + (e >> 7)) * 128 + (e & 127), Bs + e);
  }
  __syncthreads();

  f32x4 acc[4][4] = {};
#pragma unroll
  for (int kk = 0; kk < 4; ++kk) {
    short8 af[4], bfr[4];
#pragma unroll
    for (int i = 0; i < 4; ++i)
      af[i] = *(const short8*)&As[(wm + i * 16 + lc) * 128 + kk * 32 + quad * 8];
#pragma unroll
    for (int j = 0; j < 4; ++j)
      bfr[j] = *(const short8*)&Bs[(wn + j * 16 + lc) * 128 + kk * 32 + quad * 8];
#pragma unroll
    for (int i = 0; i < 4; ++i)
#pragma unroll
      for (int j = 0; j < 4; ++j)
        acc[i][j] = __builtin_amdgcn_mfma_f32_16x16x32_bf16(af[i], bfr[j], acc[i][j], 0, 0, 0);
  }

  const float SCALE = 0.025515518153991442f;  // 1/sqrt(1536)
#pragma unroll
  for (int i = 0; i < 4; ++i) {
    const int gm = m0 + wm + i * 16 + lr;  // s'
#pragma unroll
    for (int j = 0; j < 4; ++j) {
      const int gn = n0 + wn + j * 16 + lc;  // s
      us4 pk;
#pragma unroll
      for (int r2 = 0; r2 < 4; ++r2) {
        int mm = gm + r2;
        float v = 0.0f;
        if (mm <= gn) {
          float tt = fmaf(acc[i][j][r2], SCALE, btab[gn - mm]);
          tt = fmaxf(tt, 0.0f);
          v = tt * tt;
        }
        pk[r2] = f2bf(v);
      }
      *(us4*)&Pz[(size_t)gn * 2048 + gm] = pk;
    }
  }
}

// ---------------- OG: (P@v)*gate, 128x128, XCD-aware LPT ----------------
__global__ __launch_bounds__(256) void og_k(
    const unsigned short* __restrict__ Vt,     // [4][1536][2048]
    const unsigned short* __restrict__ P,      // [4][2048][2048]
    const unsigned short* __restrict__ gateT,  // [1536][8192]
    unsigned short* __restrict__ og) {         // [8192][1536]
  __shared__ unsigned short As[128 * 64];
  __shared__ unsigned short Bs[128 * 64];
  const int t = threadIdx.x, l = t & 63, w = t >> 6;
  const int id = blockIdx.x;
  const int bblk = id / 96, rr = id % 96;
  const int xcd = rr & 7, mi = rr >> 3;
  const int half = xcd >> 2, z = xcd & 3;
  const int nt = 15 - 2 * bblk - (half ^ (bblk & 1));
  const int m0 = mi * 128;    // I tile
  const int n0 = nt * 128;    // S tile
  const int kend = n0 + 128;  // causal extent over S'
  const unsigned short* A = Vt + (size_t)z * 1536 * 2048;
  const unsigned short* B = P + (size_t)z * 2048 * 2048;
  const int wm = (w >> 1) * 64, wn = (w & 1) * 64;
  const int quad = l >> 4, lr = quad * 4, lc = l & 15;

  f32x4 acc[4][4] = {};
  for (int ko = 0; ko < kend; ko += 64) {
    stage_bf(A, 2048, m0, ko, As, w, l);
    stage_bf(B, 2048, n0, ko, Bs, w, l);
    __syncthreads();
    mfma_bf(As, Bs, acc, wm, wn, quad, lc);
    __syncthreads();
  }
#pragma unroll
  for (int i = 0; i < 4; ++i) {
    const int gm = m0 + wm + i * 16 + lr;  // i
#pragma unroll
    for (int j = 0; j < 4; ++j) {
      const int gn = n0 + wn + j * 16 + lc;  // s
      us4 pk;
#pragma unroll
      for (int r2 = 0; r2 < 4; ++r2) {
        float g = bf2f(gateT[(size_t)(gm + r2) * 8192 + z * 2048 + gn]);
        pk[r2] = f2bf(acc[i][j][r2] * g);
      }
      *(us4*)&og[((size_t)z * 2048 + gn) * 1536 + gm] = pk;
    }
  }
}

// ---------------- GOUT: og @ outW + ob, 64x128 tiles ----------------
__global__ __launch_bounds__(256) void gout_k(
    const unsigned short* __restrict__ A,   // oWt 768x1536
    const unsigned short* __restrict__ Bt,  // og 8192x1536
    float* __restrict__ out, const float* __restrict__ o_b) {
  __shared__ unsigned short As[64 * 64];   // 8 KB
  __shared__ unsigned short Bs[128 * 64];  // 16 KB
  const int t = threadIdx.x, l = t & 63, w = t >> 6;
  // 768 blocks (3/CU): xcd = id&7; n sliced per XCD -> og slab L2-resident
  const int id = blockIdx.x;
  const int xcd = id & 7, rest = id >> 3;
  const int m = rest % 12, ng = rest / 12;
  const int m0 = m * 64, n0 = (ng * 8 + xcd) * 128;
  const int wm = (w >> 1) * 32, wn = (w & 1) * 64;
  const int quad = l >> 4, lr = quad * 4, lc = l & 15;

  f32x4 acc[2][4] = {};
  for (int ko = 0; ko < 1536; ko += 64) {
    stage_bf64(A, 1536, m0, ko, As, w, l);
    stage_bf(Bt, 1536, n0, ko, Bs, w, l);
    __syncthreads();
#pragma unroll
    for (int kk = 0; kk < 2; ++kk) {
      short8 af[2], bfr[4];
#pragma unroll
      for (int i = 0; i < 2; ++i)
        af[i] = *(const short8*)&As[(wm + i * 16 + lc) * 64 + kk * 32 + quad * 8];
#pragma unroll
      for (int j = 0; j < 4; ++j)
        bfr[j] = *(const short8*)&Bs[(wn + j * 16 + lc) * 64 + kk * 32 + quad * 8];
#pragma unroll
      for (int i = 0; i < 2; ++i)
#pragma unroll
        for (int j = 0; j < 4; ++j)
          acc[i][j] = __builtin_amdgcn_mfma_f32_16x16x32_bf16(af[i], bfr[j], acc[i][j], 0, 0, 0);
    }
    __syncthreads();
  }
#pragma unroll
  for (int i = 0; i < 2; ++i) {
    const int gm = m0 + wm + i * 16 + lr;  // d
#pragma unroll
    for (int j = 0; j < 4; ++j) {
      const int gn = n0 + wn + j * 16 + lc;  // bs
      fl4 ob = *(const fl4*)&o_b[gm];
      fl4 res;
#pragma unroll
      for (int r2 = 0; r2 < 4; ++r2) res[r2] = acc[i][j][r2] + ob[r2];
      *(fl4*)&out[(size_t)gn * 768 + gm] = res;
    }
  }
}

// ---------------- prep ----------------
__global__ void cvt_bf16(const float* __restrict__ in, unsigned short* __restrict__ out, int n) {
  int i = (blockIdx.x * blockDim.x + threadIdx.x) * 4;
  if (i < n) {
    fl4 v = *(const fl4*)&in[i];
    us4 o;
#pragma unroll
    for (int r = 0; r < 4; ++r) o[r] = f2bf(v[r]);
    *(us4*)&out[i] = o;
  }
}

// z<4: weight transposes; z==4: bias table.
__global__ void transpose_cvt4(const float* __restrict__ s0, unsigned short* __restrict__ d0,
                               const float* __restrict__ s1, unsigned short* __restrict__ d1,
                               const float* __restrict__ s2, unsigned short* __restrict__ d2,
                               const float* __restrict__ s3, unsigned short* __restrict__ d3,
                               const float* __restrict__ rel_emb, float* __restrict__ tab) {
  if (blockIdx.z == 4) {
    if (blockIdx.x == 0 && blockIdx.y == 0) {
      int d = threadIdx.y * 32 + threadIdx.x;  // 256 threads
#pragma unroll
      for (int rep = 0; rep < 8; ++rep, d += 256) {
        int bucket;
        if (d < 16) {
          bucket = d;
        } else {
          float n = (float)d;
          int vl = 16 + (int)((logf(n * 0.0625f) / logf(8.0f)) * 16.0f);
          bucket = vl < 31 ? vl : 31;
        }
        tab[d] = rel_emb[bucket] * 11.3137085f;
      }
    }
    return;
  }
  __shared__ float tile[32][33];
  const float* in;
  unsigned short* out;
  int K_, N_, bxm, bym;
  switch (blockIdx.z) {
    case 0: in = s0; out = d0; K_ = 768; N_ = 1536; bxm = 48; bym = 24; break;
    case 1: in = s1; out = d1; K_ = 768; N_ = 1536; bxm = 48; bym = 24; break;
    case 2: in = s2; out = d2; K_ = 768; N_ = 128;  bxm = 4;  bym = 24; break;
    default: in = s3; out = d3; K_ = 1536; N_ = 768; bxm = 24; bym = 48; break;
  }
  if ((int)blockIdx.x >= bxm || (int)blockIdx.y >= bym) return;
  int bn = blockIdx.x * 32, bk = blockIdx.y * 32;
  int tx = threadIdx.x, ty = threadIdx.y;
#pragma unroll
  for (int i2 = 0; i2 < 32; i2 += 8)
    tile[ty + i2][tx] = in[(size_t)(bk + ty + i2) * N_ + (bn + tx)];
  __syncthreads();
#pragma unroll
  for (int i2 = 0; i2 < 32; i2 += 8)
    out[(size_t)(bn + ty + i2) * K_ + (bk + tx)] = f2bf(tile[tx][ty + i2]);
}

extern "C" void kernel_launch(void* const* d_in, const int* in_sizes, int n_in,
                              void* d_out, int out_size, void* d_ws, size_t ws_size,
                              hipStream_t stream) {
  const float* x    = (const float*)d_in[0];
  const float* vW   = (const float*)d_in[1];
  const float* v_b  = (const float*)d_in[2];
  const float* gW   = (const float*)d_in[3];
  const float* g_b  = (const float*)d_in[4];
  const float* inW  = (const float*)d_in[5];
  const float* in_b = (const float*)d_in[6];
  const float* q_g  = (const float*)d_in[7];
  const float* q_be = (const float*)d_in[8];
  const float* k_g  = (const float*)d_in[9];
  const float* k_be = (const float*)d_in[10];
  const float* oW   = (const float*)d_in[11];
  const float* o_b  = (const float*)d_in[12];
  const float* rel  = (const float*)d_in[13];

  char* p = (char*)d_ws;
  auto alloc = [&](size_t bytes) -> char* {
    char* r = p;
    p += (bytes + 255) & ~(size_t)255;
    return r;
  };
  unsigned short* x_bf   = (unsigned short*)alloc(8192ull * 768 * 2);
  unsigned short* wstack = (unsigned short*)alloc(3200ull * 768 * 2);  // [vWt;gWt;inWt]
  unsigned short* vWt  = wstack;
  unsigned short* gWt  = wstack + 1536ull * 768;
  unsigned short* inWt = wstack + 3072ull * 768;
  unsigned short* oWt  = (unsigned short*)alloc(768ull * 1536 * 2);
  unsigned short* wq   = (unsigned short*)alloc(8192ull * 128 * 2);
  unsigned short* wk   = (unsigned short*)alloc(8192ull * 128 * 2);
  unsigned short* vt   = (unsigned short*)alloc(4ull * 1536 * 2048 * 2);
  unsigned short* gateT= (unsigned short*)alloc(1536ull * 8192 * 2);
  unsigned short* P    = (unsigned short*)alloc(4ull * 2048 * 2048 * 2);
  unsigned short* og   = (unsigned short*)alloc(8192ull * 1536 * 2);
  float* btab          = (float*)alloc(2048 * 4);

  cvt_bf16<<<dim3(6144), dim3(256), 0, stream>>>(x, x_bf, 8192 * 768);
  transpose_cvt4<<<dim3(48, 48, 5), dim3(32, 8), 0, stream>>>(vW, vWt, gW, gWt, inW, inWt,
                                                              oW, oWt, rel, btab);

  g123_k<<<dim3(800), 256, 0, stream>>>(x_bf, wstack, vt, gateT, wq, wk,
                                        v_b, g_b, in_b, q_g, q_be, k_g, k_be);
  scores_k<<<dim3(136, 1, 4), 256, 0, stream>>>(wk, wq, P, btab);
  og_k<<<dim3(768), 256, 0, stream>>>(vt, P, gateT, og);
  gout_k<<<dim3(768), 256, 0, stream>>>(oWt, og, (float*)d_out, o_b);
}

// Round 8
// 288.564 us; speedup vs baseline: 1.1672x; 1.1099x over previous
//
#include <hip/hip_runtime.h>

// GatedAttentionUnit: B=4, S=2048, D=768, I=1536, H=128. All-bf16 MFMA pipeline.
// R8: XOR bank-swizzle on all LDS tiles. Rows are 64/128 bf16 = multiple of 32
// banks, so naive layout gives 16-way conflicts on ds_read_b128 (1.1e7 conflict
// cycles/dispatch in R7 — doubles LDS read time, throttles the global_load_lds
// write port too). global_load_lds forbids padding; instead lane for LDS chunk
// (row,k') fetches global chunk k'^(row&7); readers address chunk k^(row&7).
//  G123 : x @ [vW gW inW] (256x128 tiles) -> vt (transposed), gateT, q, k
//  SC   : k@q^T (K=128 single-stage); P = relu(./sqrt(I)+bias)^2, triangular grid
//  OG   : og = (P@v)*gate, 128x128, XCD-aware LPT flat grid, causal K-clamp
//  GOUT : out = og@outW + ob (fp32), 64x128 tiles, 768 blocks

typedef short short8 __attribute__((ext_vector_type(8)));
typedef float f32x4 __attribute__((ext_vector_type(4)));
typedef unsigned short us4 __attribute__((ext_vector_type(4)));
typedef float fl4 __attribute__((ext_vector_type(4)));

__device__ __forceinline__ unsigned short f2bf(float f) {
  unsigned u = __builtin_bit_cast(unsigned, f);
  u += 0x7FFFu + ((u >> 16) & 1u);
  return (unsigned short)(u >> 16);
}
__device__ __forceinline__ float bf2f(unsigned short b) {
  return __builtin_bit_cast(float, ((unsigned)b) << 16);
}
__device__ __forceinline__ float silu_f(float x) { return x / (1.0f + __expf(-x)); }

__device__ __forceinline__ void gl_lds16(const void* gp, void* lp) {
  __builtin_amdgcn_global_load_lds((const __attribute__((address_space(1))) void*)gp,
                                   (__attribute__((address_space(3))) void*)lp, 16, 0, 0);
}

// Stage CALLS*32 rows x 64 cols bf16, XOR-swizzled: LDS chunk (row,k') holds
// global chunk k'^(row&7). LDS dst stays base+lane*16B (required pattern).
template <int CALLS>
__device__ __forceinline__ void stage_sw(const unsigned short* __restrict__ g,
                                         int row_stride, int r0, int ko,
                                         unsigned short* lds, int w, int l) {
#pragma unroll
  for (int c = 0; c < CALLS; ++c) {
    int e = ((w * CALLS + c) << 9) + l * 8;
    int row = e >> 6;
    int gcol = ((((e >> 3) & 7) ^ (row & 7)) << 3);
    gl_lds16(g + (size_t)(r0 + row) * row_stride + (ko + gcol), lds + e);
  }
}
// 128 rows x 128 cols (scores): 16 chunks/row, swizzle low 3 bits.
__device__ __forceinline__ void stage_sw128(const unsigned short* __restrict__ g, int r0,
                                            unsigned short* lds, int w, int l) {
#pragma unroll
  for (int c = 0; c < 8; ++c) {
    int e = ((w * 8 + c) << 9) + l * 8;
    int row = e >> 7;
    int gcol = ((((e >> 3) & 15) ^ (row & 7)) << 3);
    gl_lds16(g + (size_t)(r0 + row) * 128 + gcol, lds + e);
  }
}

// 128x128 K-step over BK=64 (swizzled tiles): 32 MFMA/wave
__device__ __forceinline__ void mfma_sw(const unsigned short* As, const unsigned short* Bs,
                                        f32x4 acc[4][4], int wm, int wn, int quad, int lc) {
  const int x7 = lc & 7;
#pragma unroll
  for (int kk = 0; kk < 2; ++kk) {
    short8 af[4], bfr[4];
#pragma unroll
    for (int i = 0; i < 4; ++i)
      af[i] = *(const short8*)&As[(wm + i * 16 + lc) * 64 + (((kk * 4 + quad) ^ x7) << 3)];
#pragma unroll
    for (int j = 0; j < 4; ++j)
      bfr[j] = *(const short8*)&Bs[(wn + j * 16 + lc) * 64 + (((kk * 4 + quad) ^ x7) << 3)];
#pragma unroll
    for (int i = 0; i < 4; ++i)
#pragma unroll
      for (int j = 0; j < 4; ++j)
        acc[i][j] = __builtin_amdgcn_mfma_f32_16x16x32_bf16(af[i], bfr[j], acc[i][j], 0, 0, 0);
  }
}

// ---------------- G123: x @ [vW gW inW], 256x128 tiles ----------------
__global__ __launch_bounds__(256, 2) void g123_k(
    const unsigned short* __restrict__ X,    // 8192x768
    const unsigned short* __restrict__ Wst,  // 3200x768 (stacked W^T)
    unsigned short* __restrict__ vt,         // [4][1536][2048]
    unsigned short* __restrict__ gateT,      // [1536][8192]
    unsigned short* __restrict__ wq,         // [8192][128]
    unsigned short* __restrict__ wk,
    const float* __restrict__ v_b, const float* __restrict__ g_b,
    const float* __restrict__ in_b, const float* __restrict__ q_g,
    const float* __restrict__ q_be, const float* __restrict__ k_g,
    const float* __restrict__ k_be) {
  __shared__ unsigned short As[256 * 64];  // 32 KB
  __shared__ unsigned short Bs[128 * 64];  // 16 KB
  const int t = threadIdx.x, l = t & 63, w = t >> 6;
  const int id = blockIdx.x;
  const int xcd = id & 7, rest = id >> 3;
  const int n = rest % 25, m = (rest / 25) * 8 + xcd;  // m in 0..31
  const int m0 = m * 256, n0 = n * 128;
  const int wm = (w >> 1) * 128, wn = (w & 1) * 64;
  const int quad = l >> 4, lr = quad * 4, lc = l & 15;
  const int x7 = lc & 7;

  f32x4 acc[8][4] = {};
  for (int ko = 0; ko < 768; ko += 64) {
    stage_sw<8>(X, 768, m0, ko, As, w, l);
    stage_sw<4>(Wst, 768, n0, ko, Bs, w, l);
    __syncthreads();
#pragma unroll
    for (int kk = 0; kk < 2; ++kk) {
      short8 af[8], bfr[4];
#pragma unroll
      for (int i = 0; i < 8; ++i)
        af[i] = *(const short8*)&As[(wm + i * 16 + lc) * 64 + (((kk * 4 + quad) ^ x7) << 3)];
#pragma unroll
      for (int j = 0; j < 4; ++j)
        bfr[j] = *(const short8*)&Bs[(wn + j * 16 + lc) * 64 + (((kk * 4 + quad) ^ x7) << 3)];
#pragma unroll
      for (int i = 0; i < 8; ++i)
#pragma unroll
        for (int j = 0; j < 4; ++j)
          acc[i][j] = __builtin_amdgcn_mfma_f32_16x16x32_bf16(af[i], bfr[j], acc[i][j], 0, 0, 0);
    }
    __syncthreads();
  }

#pragma unroll
  for (int i = 0; i < 8; ++i) {
    const int gm = m0 + wm + i * 16 + lr;  // bs row
#pragma unroll
    for (int j = 0; j < 4; ++j) {
      const int gn = n0 + wn + j * 16 + lc;  // stacked col
      f32x4 a = acc[i][j];
      if (n0 < 1536) {  // v -> vt[b][i][s], 4 consecutive s
        float bv = v_b[gn];
        us4 pk;
#pragma unroll
        for (int r = 0; r < 4; ++r) pk[r] = f2bf(silu_f(a[r] + bv));
        size_t off = (size_t)(gm >> 11) * (1536 * 2048) + (size_t)gn * 2048 + (gm & 2047);
        *(us4*)&vt[off] = pk;
      } else if (n0 < 3072) {  // gateT[i][bs]
        float bv = g_b[gn - 1536];
        us4 pk;
#pragma unroll
        for (int r = 0; r < 4; ++r) pk[r] = f2bf(silu_f(a[r] + bv));
        *(us4*)&gateT[(size_t)(gn - 1536) * 8192 + gm] = pk;
      } else {  // qk: scalar bf16 stores (lanes span h -> coalesced)
        int h = gn - 3072;
        float bb = in_b[h], qg = q_g[h], qb = q_be[h], kg = k_g[h], kb = k_be[h];
#pragma unroll
        for (int r = 0; r < 4; ++r) {
          float s = silu_f(a[r] + bb);
          wq[(size_t)(gm + r) * 128 + h] = f2bf(s * qg + qb);
          wk[(size_t)(gm + r) * 128 + h] = f2bf(s * kg + kb);
        }
      }
    }
  }
}

// ---------------- SC: k@q^T, K=128 fully staged, 1 barrier ----------------
__global__ __launch_bounds__(256) void scores_k(
    const unsigned short* __restrict__ wk, const unsigned short* __restrict__ wq,
    unsigned short* __restrict__ P, const float* __restrict__ btab) {
  __shared__ unsigned short As[128 * 128];  // 32 KB
  __shared__ unsigned short Bs[128 * 128];
  const int t = threadIdx.x, l = t & 63, w = t >> 6;
  const int z = blockIdx.z;
  int ti = blockIdx.x;  // triangular decode: c <= r
  int r = (int)((sqrtf((float)(8 * ti + 1)) - 1.0f) * 0.5f);
  if ((r + 1) * (r + 2) / 2 <= ti) ++r;
  int c = ti - r * (r + 1) / 2;
  const int m0 = c * 128, n0 = r * 128;
  const unsigned short* A = wk + (size_t)z * 2048 * 128;
  const unsigned short* Bt = wq + (size_t)z * 2048 * 128;
  unsigned short* Pz = P + (size_t)z * 2048 * 2048;
  const int wm = (w >> 1) * 64, wn = (w & 1) * 64;
  const int quad = l >> 4, lr = quad * 4, lc = l & 15;
  const int x7 = lc & 7;

  stage_sw128(A, m0, As, w, l);
  stage_sw128(Bt, n0, Bs, w, l);
  __syncthreads();

  f32x4 acc[4][4] = {};
#pragma unroll
  for (int kk = 0; kk < 4; ++kk) {
    short8 af[4], bfr[4];
#pragma unroll
    for (int i = 0; i < 4; ++i)
      af[i] = *(const short8*)&As[(wm + i * 16 + lc) * 128 + (((kk * 4 + quad) ^ x7) << 3)];
#pragma unroll
    for (int j = 0; j < 4; ++j)
      bfr[j] = *(const short8*)&Bs[(wn + j * 16 + lc) * 128 + (((kk * 4 + quad) ^ x7) << 3)];
#pragma unroll
    for (int i = 0; i < 4; ++i)
#pragma unroll
      for (int j = 0; j < 4; ++j)
        acc[i][j] = __builtin_amdgcn_mfma_f32_16x16x32_bf16(af[i], bfr[j], acc[i][j], 0, 0, 0);
  }

  const float SCALE = 0.025515518153991442f;  // 1/sqrt(1536)
#pragma unroll
  for (int i = 0; i < 4; ++i) {
    const int gm = m0 + wm + i * 16 + lr;  // s'
#pragma unroll
    for (int j = 0; j < 4; ++j) {
      const int gn = n0 + wn + j * 16 + lc;  // s
      us4 pk;
#pragma unroll
      for (int r2 = 0; r2 < 4; ++r2) {
        int mm = gm + r2;
        float v = 0.0f;
        if (mm <= gn) {
          float tt = fmaf(acc[i][j][r2], SCALE, btab[gn - mm]);
          tt = fmaxf(tt, 0.0f);
          v = tt * tt;
        }
        pk[r2] = f2bf(v);
      }
      *(us4*)&Pz[(size_t)gn * 2048 + gm] = pk;
    }
  }
}

// ---------------- OG: (P@v)*gate, 128x128, XCD-aware LPT ----------------
__global__ __launch_bounds__(256) void og_k(
    const unsigned short* __restrict__ Vt,     // [4][1536][2048]
    const unsigned short* __restrict__ P,      // [4][2048][2048]
    const unsigned short* __restrict__ gateT,  // [1536][8192]
    unsigned short* __restrict__ og) {         // [8192][1536]
  __shared__ unsigned short As[128 * 64];
  __shared__ unsigned short Bs[128 * 64];
  const int t = threadIdx.x, l = t & 63, w = t >> 6;
  const int id = blockIdx.x;
  const int bblk = id / 96, rr = id % 96;
  const int xcd = rr & 7, mi = rr >> 3;
  const int half = xcd >> 2, z = xcd & 3;
  const int nt = 15 - 2 * bblk - (half ^ (bblk & 1));
  const int m0 = mi * 128;    // I tile
  const int n0 = nt * 128;    // S tile
  const int kend = n0 + 128;  // causal extent over S'
  const unsigned short* A = Vt + (size_t)z * 1536 * 2048;
  const unsigned short* B = P + (size_t)z * 2048 * 2048;
  const int wm = (w >> 1) * 64, wn = (w & 1) * 64;
  const int quad = l >> 4, lr = quad * 4, lc = l & 15;

  f32x4 acc[4][4] = {};
  for (int ko = 0; ko < kend; ko += 64) {
    stage_sw<4>(A, 2048, m0, ko, As, w, l);
    stage_sw<4>(B, 2048, n0, ko, Bs, w, l);
    __syncthreads();
    mfma_sw(As, Bs, acc, wm, wn, quad, lc);
    __syncthreads();
  }
#pragma unroll
  for (int i = 0; i < 4; ++i) {
    const int gm = m0 + wm + i * 16 + lr;  // i
#pragma unroll
    for (int j = 0; j < 4; ++j) {
      const int gn = n0 + wn + j * 16 + lc;  // s
      us4 pk;
#pragma unroll
      for (int r2 = 0; r2 < 4; ++r2) {
        float g = bf2f(gateT[(size_t)(gm + r2) * 8192 + z * 2048 + gn]);
        pk[r2] = f2bf(acc[i][j][r2] * g);
      }
      *(us4*)&og[((size_t)z * 2048 + gn) * 1536 + gm] = pk;
    }
  }
}

// ---------------- GOUT: og @ outW + ob, 64x128 tiles ----------------
__global__ __launch_bounds__(256) void gout_k(
    const unsigned short* __restrict__ A,   // oWt 768x1536
    const unsigned short* __restrict__ Bt,  // og 8192x1536
    float* __restrict__ out, const float* __restrict__ o_b) {
  __shared__ unsigned short As[64 * 64];   // 8 KB
  __shared__ unsigned short Bs[128 * 64];  // 16 KB
  const int t = threadIdx.x, l = t & 63, w = t >> 6;
  const int id = blockIdx.x;
  const int xcd = id & 7, rest = id >> 3;
  const int m = rest % 12, ng = rest / 12;
  const int m0 = m * 64, n0 = (ng * 8 + xcd) * 128;
  const int wm = (w >> 1) * 32, wn = (w & 1) * 64;
  const int quad = l >> 4, lr = quad * 4, lc = l & 15;
  const int x7 = lc & 7;

  f32x4 acc[2][4] = {};
  for (int ko = 0; ko < 1536; ko += 64) {
    stage_sw<2>(A, 1536, m0, ko, As, w, l);
    stage_sw<4>(Bt, 1536, n0, ko, Bs, w, l);
    __syncthreads();
#pragma unroll
    for (int kk = 0; kk < 2; ++kk) {
      short8 af[2], bfr[4];
#pragma unroll
      for (int i = 0; i < 2; ++i)
        af[i] = *(const short8*)&As[(wm + i * 16 + lc) * 64 + (((kk * 4 + quad) ^ x7) << 3)];
#pragma unroll
      for (int j = 0; j < 4; ++j)
        bfr[j] = *(const short8*)&Bs[(wn + j * 16 + lc) * 64 + (((kk * 4 + quad) ^ x7) << 3)];
#pragma unroll
      for (int i = 0; i < 2; ++i)
#pragma unroll
        for (int j = 0; j < 4; ++j)
          acc[i][j] = __builtin_amdgcn_mfma_f32_16x16x32_bf16(af[i], bfr[j], acc[i][j], 0, 0, 0);
    }
    __syncthreads();
  }
#pragma unroll
  for (int i = 0; i < 2; ++i) {
    const int gm = m0 + wm + i * 16 + lr;  // d
#pragma unroll
    for (int j = 0; j < 4; ++j) {
      const int gn = n0 + wn + j * 16 + lc;  // bs
      fl4 ob = *(const fl4*)&o_b[gm];
      fl4 res;
#pragma unroll
      for (int r2 = 0; r2 < 4; ++r2) res[r2] = acc[i][j][r2] + ob[r2];
      *(fl4*)&out[(size_t)gn * 768 + gm] = res;
    }
  }
}

// ---------------- prep ----------------
__global__ void cvt_bf16(const float* __restrict__ in, unsigned short* __restrict__ out, int n) {
  int i = (blockIdx.x * blockDim.x + threadIdx.x) * 4;
  if (i < n) {
    fl4 v = *(const fl4*)&in[i];
    us4 o;
#pragma unroll
    for (int r = 0; r < 4; ++r) o[r] = f2bf(v[r]);
    *(us4*)&out[i] = o;
  }
}

// z<4: weight transposes; z==4: bias table.
__global__ void transpose_cvt4(const float* __restrict__ s0, unsigned short* __restrict__ d0,
                               const float* __restrict__ s1, unsigned short* __restrict__ d1,
                               const float* __restrict__ s2, unsigned short* __restrict__ d2,
                               const float* __restrict__ s3, unsigned short* __restrict__ d3,
                               const float* __restrict__ rel_emb, float* __restrict__ tab) {
  if (blockIdx.z == 4) {
    if (blockIdx.x == 0 && blockIdx.y == 0) {
      int d = threadIdx.y * 32 + threadIdx.x;  // 256 threads
#pragma unroll
      for (int rep = 0; rep < 8; ++rep, d += 256) {
        int bucket;
        if (d < 16) {
          bucket = d;
        } else {
          float n = (float)d;
          int vl = 16 + (int)((logf(n * 0.0625f) / logf(8.0f)) * 16.0f);
          bucket = vl < 31 ? vl : 31;
        }
        tab[d] = rel_emb[bucket] * 11.3137085f;
      }
    }
    return;
  }
  __shared__ float tile[32][33];
  const float* in;
  unsigned short* out;
  int K_, N_, bxm, bym;
  switch (blockIdx.z) {
    case 0: in = s0; out = d0; K_ = 768; N_ = 1536; bxm = 48; bym = 24; break;
    case 1: in = s1; out = d1; K_ = 768; N_ = 1536; bxm = 48; bym = 24; break;
    case 2: in = s2; out = d2; K_ = 768; N_ = 128;  bxm = 4;  bym = 24; break;
    default: in = s3; out = d3; K_ = 1536; N_ = 768; bxm = 24; bym = 48; break;
  }
  if ((int)blockIdx.x >= bxm || (int)blockIdx.y >= bym) return;
  int bn = blockIdx.x * 32, bk = blockIdx.y * 32;
  int tx = threadIdx.x, ty = threadIdx.y;
#pragma unroll
  for (int i2 = 0; i2 < 32; i2 += 8)
    tile[ty + i2][tx] = in[(size_t)(bk + ty + i2) * N_ + (bn + tx)];
  __syncthreads();
#pragma unroll
  for (int i2 = 0; i2 < 32; i2 += 8)
    out[(size_t)(bn + ty + i2) * K_ + (bk + tx)] = f2bf(tile[tx][ty + i2]);
}

extern "C" void kernel_launch(void* const* d_in, const int* in_sizes, int n_in,
                              void* d_out, int out_size, void* d_ws, size_t ws_size,
                              hipStream_t stream) {
  const float* x    = (const float*)d_in[0];
  const float* vW   = (const float*)d_in[1];
  const float* v_b  = (const float*)d_in[2];
  const float* gW   = (const float*)d_in[3];
  const float* g_b  = (const float*)d_in[4];
  const float* inW  = (const float*)d_in[5];
  const float* in_b = (const float*)d_in[6];
  const float* q_g  = (const float*)d_in[7];
  const float* q_be = (const float*)d_in[8];
  const float* k_g  = (const float*)d_in[9];
  const float* k_be = (const float*)d_in[10];
  const float* oW   = (const float*)d_in[11];
  const float* o_b  = (const float*)d_in[12];
  const float* rel  = (const float*)d_in[13];

  char* p = (char*)d_ws;
  auto alloc = [&](size_t bytes) -> char* {
    char* r = p;
    p += (bytes + 255) & ~(size_t)255;
    return r;
  };
  unsigned short* x_bf   = (unsigned short*)alloc(8192ull * 768 * 2);
  unsigned short* wstack = (unsigned short*)alloc(3200ull * 768 * 2);  // [vWt;gWt;inWt]
  unsigned short* vWt  = wstack;
  unsigned short* gWt  = wstack + 1536ull * 768;
  unsigned short* inWt = wstack + 3072ull * 768;
  unsigned short* oWt  = (unsigned short*)alloc(768ull * 1536 * 2);
  unsigned short* wq   = (unsigned short*)alloc(8192ull * 128 * 2);
  unsigned short* wk   = (unsigned short*)alloc(8192ull * 128 * 2);
  unsigned short* vt   = (unsigned short*)alloc(4ull * 1536 * 2048 * 2);
  unsigned short* gateT= (unsigned short*)alloc(1536ull * 8192 * 2);
  unsigned short* P    = (unsigned short*)alloc(4ull * 2048 * 2048 * 2);
  unsigned short* og   = (unsigned short*)alloc(8192ull * 1536 * 2);
  float* btab          = (float*)alloc(2048 * 4);

  cvt_bf16<<<dim3(6144), dim3(256), 0, stream>>>(x, x_bf, 8192 * 768);
  transpose_cvt4<<<dim3(48, 48, 5), dim3(32, 8), 0, stream>>>(vW, vWt, gW, gWt, inW, inWt,
                                                              oW, oWt, rel, btab);

  g123_k<<<dim3(800), 256, 0, stream>>>(x_bf, wstack, vt, gateT, wq, wk,
                                        v_b, g_b, in_b, q_g, q_be, k_g, k_be);
  scores_k<<<dim3(136, 1, 4), 256, 0, stream>>>(wk, wq, P, btab);
  og_k<<<dim3(768), 256, 0, stream>>>(vt, P, gateT, og);
  gout_k<<<dim3(768), 256, 0, stream>>>(oWt, og, (float*)d_out, o_b);
}